// Round 1
// baseline (116.433 us; speedup 1.0000x reference)
//
#include <hip/hip_runtime.h>

constexpr int BS = 32;
constexpr int D  = 2048;
constexpr float P = 0.5f;

constexpr int TPB = 256;            // threads per block
constexpr int NPT = 4;              // n-elements per thread (float4)
constexpr int NB  = D / (TPB*NPT);  // 2 n-blocks
constexpr int KC  = 32;             // k-chunks
constexpr int KCH = D / KC;         // 64 k per chunk

__global__ __launch_bounds__(TPB) void dropconnect_kernel(
    const float* __restrict__ x,      // (BS, D)
    const float* __restrict__ weight, // (D, D)   axes (k, n)
    const float* __restrict__ bias,   // (D,)
    const float* __restrict__ u_w,    // (BS, D, D) axes (b, k, n)
    const float* __restrict__ u_b,    // (BS, D)
    float* __restrict__ out)          // (BS, D)
{
    const int kc  = blockIdx.x;   // k-chunk
    const int nb  = blockIdx.y;   // n-block
    const int b   = blockIdx.z;   // batch
    const int tid = threadIdx.x;

    const int n0 = nb * (TPB * NPT) + tid * NPT;  // first n this thread owns
    const int k0 = kc * KCH;

    // Stage the block-uniform x chunk in LDS.
    __shared__ float xs[KCH];
    if (tid < KCH) xs[tid] = x[b * D + k0 + tid];
    __syncthreads();

    const float4* uw4 = reinterpret_cast<const float4*>(u_w);
    const float4* w4  = reinterpret_cast<const float4*>(weight);
    const int DV = D / 4;

    float acc0 = 0.f, acc1 = 0.f, acc2 = 0.f, acc3 = 0.f;

    size_t iu = ((size_t)b * D + (size_t)k0) * DV + (n0 >> 2);
    size_t iw = (size_t)k0 * DV + (n0 >> 2);

#pragma unroll 4
    for (int kk = 0; kk < KCH; ++kk) {
        const float xv = xs[kk];
        const float4 u = uw4[iu];
        const float4 w = w4[iw];
        acc0 += (u.x <= P) ? xv * w.x : 0.f;
        acc1 += (u.y <= P) ? xv * w.y : 0.f;
        acc2 += (u.z <= P) ? xv * w.z : 0.f;
        acc3 += (u.w <= P) ? xv * w.w : 0.f;
        iu += DV;
        iw += DV;
    }

    // Fold the bias term into the kc==0 partial.
    if (kc == 0) {
        const float4 ub = reinterpret_cast<const float4*>(u_b)[(b * D + n0) >> 2];
        const float4 bv = reinterpret_cast<const float4*>(bias)[n0 >> 2];
        acc0 += (ub.x <= P) ? bv.x : 0.f;
        acc1 += (ub.y <= P) ? bv.y : 0.f;
        acc2 += (ub.z <= P) ? bv.z : 0.f;
        acc3 += (ub.w <= P) ? bv.w : 0.f;
    }

    float* o = out + (size_t)b * D + n0;
    atomicAdd(o + 0, acc0);
    atomicAdd(o + 1, acc1);
    atomicAdd(o + 2, acc2);
    atomicAdd(o + 3, acc3);
}

extern "C" void kernel_launch(void* const* d_in, const int* in_sizes, int n_in,
                              void* d_out, int out_size, void* d_ws, size_t ws_size,
                              hipStream_t stream) {
    const float* x      = (const float*)d_in[0];
    const float* weight = (const float*)d_in[1];
    const float* bias   = (const float*)d_in[2];
    const float* u_w    = (const float*)d_in[3];
    const float* u_b    = (const float*)d_in[4];
    float* out = (float*)d_out;

    // d_out is poisoned (0xAA) before timing and not re-poisoned between
    // replays — zero it ourselves every call (memset node is capture-safe).
    hipMemsetAsync(out, 0, (size_t)out_size * sizeof(float), stream);

    dim3 grid(KC, NB, BS);
    dropconnect_kernel<<<grid, TPB, 0, stream>>>(x, weight, bias, u_w, u_b, out);
}